// Round 1
// baseline (2467.787 us; speedup 1.0000x reference)
//
#include <hip/hip_runtime.h>
#include <math.h>

#define SEQ   2048
#define BATCH 2
#define DM    1024
#define NH    16
#define HD    64
#define MTOT  (BATCH*SEQ)   // 4096

// ---------------- generic GEMM: C = A @ W^T + bias ----------------
// A: [MTOT, DM] row-major; W: [DM, DM] row-major (uses W[n][k]); bias[DM].
// MODE 0: write to qkv layout [B,H,T,HD];  MODE 1: write row-major [MTOT, DM].
template<int MODE>
__global__ __launch_bounds__(256)
void gemm_xwT(const float* __restrict__ A, const float* __restrict__ W,
              const float* __restrict__ bias, float* __restrict__ out)
{
    __shared__ float As[64][17];
    __shared__ float Ws[64][17];
    const int n0 = blockIdx.x * 64;
    const int m0 = blockIdx.y * 64;
    const int tid = threadIdx.x;
    const int tx = tid & 15, ty = tid >> 4;
    float acc[4][4] = {};
    for (int k0 = 0; k0 < DM; k0 += 16) {
        #pragma unroll
        for (int i = tid; i < 64 * 16; i += 256) {
            int r = i >> 4, c = i & 15;
            As[r][c] = A[(size_t)(m0 + r) * DM + k0 + c];
            Ws[r][c] = W[(size_t)(n0 + r) * DM + k0 + c];
        }
        __syncthreads();
        #pragma unroll
        for (int k = 0; k < 16; ++k) {
            float a[4], b[4];
            #pragma unroll
            for (int i = 0; i < 4; ++i) a[i] = As[ty * 4 + i][k];
            #pragma unroll
            for (int j = 0; j < 4; ++j) b[j] = Ws[tx * 4 + j][k];
            #pragma unroll
            for (int i = 0; i < 4; ++i)
                #pragma unroll
                for (int j = 0; j < 4; ++j)
                    acc[i][j] += a[i] * b[j];
        }
        __syncthreads();
    }
    #pragma unroll
    for (int i = 0; i < 4; ++i) {
        int m = m0 + ty * 4 + i;
        #pragma unroll
        for (int j = 0; j < 4; ++j) {
            int n = n0 + tx * 4 + j;
            float v = acc[i][j] + bias[n];
            if (MODE == 0) {
                int b_ = m >> 11, t = m & (SEQ - 1);
                int h = n >> 6, hd = n & 63;
                out[(((size_t)(b_ * NH + h)) * SEQ + t) * HD + hd] = v;
            } else {
                out[(size_t)m * DM + n] = v;
            }
        }
    }
}

// ---------------- scores: S = scale * Q @ K^T, mask applied ----------------
// Q,K: [B,H,T,HD]; attn out: [B,H,T,T] raw (pre-softmax) scores.
__global__ __launch_bounds__(256)
void scores_kernel(const float* __restrict__ Q, const float* __restrict__ K,
                   const int* __restrict__ mask, float* __restrict__ attn)
{
    const int bh = blockIdx.z;
    const int b  = bh >> 4;
    const int q0 = blockIdx.y * 64, k0 = blockIdx.x * 64;
    __shared__ float Qs[64][65];
    __shared__ float Ks[64][65];
    const float* Qb = Q + (size_t)bh * SEQ * HD;
    const float* Kb = K + (size_t)bh * SEQ * HD;
    for (int i = threadIdx.x; i < 64 * 64; i += 256) {
        int r = i >> 6, c = i & 63;
        Qs[r][c] = Qb[(size_t)(q0 + r) * HD + c];
        Ks[r][c] = Kb[(size_t)(k0 + r) * HD + c];
    }
    __syncthreads();
    const int tx = threadIdx.x & 15, ty = threadIdx.x >> 4;
    float acc[4][4] = {};
    #pragma unroll 4
    for (int k = 0; k < 64; ++k) {
        float a[4], b2[4];
        #pragma unroll
        for (int i = 0; i < 4; ++i) a[i] = Qs[ty * 4 + i][k];
        #pragma unroll
        for (int j = 0; j < 4; ++j) b2[j] = Ks[tx * 4 + j][k];
        #pragma unroll
        for (int i = 0; i < 4; ++i)
            #pragma unroll
            for (int j = 0; j < 4; ++j)
                acc[i][j] += a[i] * b2[j];
    }
    float* Ab = attn + (size_t)bh * SEQ * SEQ;
    #pragma unroll
    for (int i = 0; i < 4; ++i) {
        int qi = q0 + ty * 4 + i;
        #pragma unroll
        for (int j = 0; j < 4; ++j) {
            int kj = k0 + tx * 4 + j;
            float s = acc[i][j] * 0.125f;   // 1/sqrt(64)
            if (mask[b * SEQ + kj] == 0) s = -INFINITY;
            Ab[(size_t)qi * SEQ + kj] = s;
        }
    }
}

// ---------------- in-place row softmax over last dim (2048) ----------------
__global__ __launch_bounds__(256)
void softmax_kernel(float* __restrict__ attn)
{
    float* p = attn + (size_t)blockIdx.x * SEQ;
    const int tid = threadIdx.x;
    float v[8];
    float m = -INFINITY;
    #pragma unroll
    for (int j = 0; j < 8; ++j) { v[j] = p[tid + j * 256]; m = fmaxf(m, v[j]); }
    #pragma unroll
    for (int off = 32; off > 0; off >>= 1) m = fmaxf(m, __shfl_down(m, off));
    __shared__ float red[4];
    __shared__ float bcast;
    if ((tid & 63) == 0) red[tid >> 6] = m;
    __syncthreads();
    if (tid == 0) bcast = fmaxf(fmaxf(red[0], red[1]), fmaxf(red[2], red[3]));
    __syncthreads();
    m = bcast;
    float s = 0.f;
    #pragma unroll
    for (int j = 0; j < 8; ++j) { v[j] = __expf(v[j] - m); s += v[j]; }
    #pragma unroll
    for (int off = 32; off > 0; off >>= 1) s += __shfl_down(s, off);
    __syncthreads();                       // all reads of bcast/red done
    if ((tid & 63) == 0) red[tid >> 6] = s;
    __syncthreads();
    if (tid == 0) bcast = red[0] + red[1] + red[2] + red[3];
    __syncthreads();
    const float inv = 1.f / bcast;
    #pragma unroll
    for (int j = 0; j < 8; ++j) p[tid + j * 256] = v[j] * inv;
}

// ---------------- context = attn @ V ----------------
// attn: [B,H,T,T]; V: [B,H,T,HD]; ctx written as [B,T,D] row-major.
__global__ __launch_bounds__(256)
void context_kernel(const float* __restrict__ attn, const float* __restrict__ V,
                    float* __restrict__ ctx)
{
    const int bh = blockIdx.y;
    const int q0 = blockIdx.x * 64;
    const float* Ab = attn + (size_t)bh * SEQ * SEQ;
    const float* Vb = V + (size_t)bh * SEQ * HD;
    __shared__ float As[64][17];   // [qrow][k]
    __shared__ float Bs[16][65];   // [k][d]
    const int tid = threadIdx.x;
    const int tx = tid & 15, ty = tid >> 4;
    float acc[4][4] = {};
    for (int k0 = 0; k0 < SEQ; k0 += 16) {
        #pragma unroll
        for (int i = tid; i < 1024; i += 256) {
            int r = i >> 4, c = i & 15;
            As[r][c] = Ab[(size_t)(q0 + r) * SEQ + k0 + c];
        }
        #pragma unroll
        for (int i = tid; i < 1024; i += 256) {
            int r = i >> 6, c = i & 63;
            Bs[r][c] = Vb[(size_t)(k0 + r) * HD + c];
        }
        __syncthreads();
        #pragma unroll
        for (int kk = 0; kk < 16; ++kk) {
            float a[4], b2[4];
            #pragma unroll
            for (int i = 0; i < 4; ++i) a[i] = As[ty * 4 + i][kk];
            #pragma unroll
            for (int j = 0; j < 4; ++j) b2[j] = Bs[kk][tx * 4 + j];
            #pragma unroll
            for (int i = 0; i < 4; ++i)
                #pragma unroll
                for (int j = 0; j < 4; ++j)
                    acc[i][j] += a[i] * b2[j];
        }
        __syncthreads();
    }
    const int b_ = bh >> 4, h = bh & 15;
    #pragma unroll
    for (int i = 0; i < 4; ++i) {
        int t = q0 + ty * 4 + i;
        #pragma unroll
        for (int j = 0; j < 4; ++j)
            ctx[((size_t)b_ * SEQ + t) * DM + h * HD + tx * 4 + j] = acc[i][j];
    }
}

extern "C" void kernel_launch(void* const* d_in, const int* in_sizes, int n_in,
                              void* d_out, int out_size, void* d_ws, size_t ws_size,
                              hipStream_t stream)
{
    const float* x   = (const float*)d_in[0];
    const int*  mask = (const int*)d_in[1];
    const float* Wq  = (const float*)d_in[2];
    const float* bq  = (const float*)d_in[3];
    const float* Wk  = (const float*)d_in[4];
    const float* bk  = (const float*)d_in[5];
    const float* Wv  = (const float*)d_in[6];
    const float* bv  = (const float*)d_in[7];
    const float* Wo  = (const float*)d_in[8];
    const float* bo  = (const float*)d_in[9];

    float* out  = (float*)d_out;                       // [B,T,D]
    float* attn = out + (size_t)BATCH * SEQ * DM;      // [B,H,T,T]

    float* Q   = (float*)d_ws;                         // [B,H,T,HD] each
    float* K   = Q + (size_t)BATCH * NH * SEQ * HD;
    float* V   = K + (size_t)BATCH * NH * SEQ * HD;
    float* ctx = V + (size_t)BATCH * NH * SEQ * HD;    // [B,T,D]

    dim3 g1(DM / 64, MTOT / 64);
    gemm_xwT<0><<<g1, 256, 0, stream>>>(x, Wq, bq, Q);
    gemm_xwT<0><<<g1, 256, 0, stream>>>(x, Wk, bk, K);
    gemm_xwT<0><<<g1, 256, 0, stream>>>(x, Wv, bv, V);

    dim3 g2(SEQ / 64, SEQ / 64, BATCH * NH);
    scores_kernel<<<g2, 256, 0, stream>>>(Q, K, mask, attn);

    softmax_kernel<<<dim3(BATCH * NH * SEQ), 256, 0, stream>>>(attn);

    dim3 g4(SEQ / 64, BATCH * NH);
    context_kernel<<<g4, 256, 0, stream>>>(attn, V, ctx);

    gemm_xwT<1><<<g1, 256, 0, stream>>>(ctx, Wo, bo, out);
}

// Round 2
// 1132.294 us; speedup vs baseline: 2.1795x; 2.1795x over previous
//
#include <hip/hip_runtime.h>
#include <math.h>

#define SEQ   2048
#define BATCH 2
#define DM    1024
#define NH    16
#define HD    64
#define MTOT  (BATCH*SEQ)   // 4096

typedef __bf16 bf16_t;
typedef __bf16 bf16x4 __attribute__((ext_vector_type(4)));
typedef __bf16 bf16x8 __attribute__((ext_vector_type(8)));
typedef float  f32x4  __attribute__((ext_vector_type(4)));

// ---------------- fp32 -> bf16 conversion (n % 4 == 0) ----------------
__global__ __launch_bounds__(256)
void cvt_bf16(const float* __restrict__ in, bf16_t* __restrict__ out, int n)
{
    int i = (blockIdx.x * 256 + threadIdx.x) * 4;
    if (i >= n) return;
    float4 f = *(const float4*)(in + i);
    bf16x4 h;
    h.x = (__bf16)f.x; h.y = (__bf16)f.y; h.z = (__bf16)f.z; h.w = (__bf16)f.w;
    *(bf16x4*)(out + i) = h;
}

// ---------------- MFMA GEMM: C = A @ W^T + bias ----------------
// A: [MTOT, DM] bf16 row-major; W: [DM, DM] bf16 row-major (row n = output col n).
// 128x128 tile, BK=32, 4 waves each doing a 64x64 subtile (4x4 MFMAs of 16x16x32).
// MODE 0: write bf16 to qkv layout [B,H,T,HD]; MODE 1: write fp32 row-major [MTOT, DM].
template<int MODE>
__global__ __launch_bounds__(256)
void gemm_bt(const bf16_t* __restrict__ A, const bf16_t* __restrict__ W,
             const float* __restrict__ bias, void* __restrict__ outp)
{
    __shared__ __align__(16) bf16_t As[128 * 32];
    __shared__ __align__(16) bf16_t Bs[128 * 32];
    const int n0 = blockIdx.x * 128, m0 = blockIdx.y * 128;
    const int tid = threadIdx.x, lane = tid & 63, wave = tid >> 6;
    const int wm = (wave >> 1) * 64, wn = (wave & 1) * 64;
    const int sr = tid >> 2, sc = (tid & 3) * 8;   // staging: row, k-chunk
    const int fr = lane & 15, fk = (lane >> 4) * 8; // fragment: row-in-16, k-offset
    f32x4 acc[4][4] = {};
    for (int k0 = 0; k0 < DM; k0 += 32) {
        *(uint4*)&As[sr * 32 + sc]        = *(const uint4*)&A[(size_t)(m0 + sr) * DM + k0 + sc];
        *(uint4*)&As[(sr + 64) * 32 + sc] = *(const uint4*)&A[(size_t)(m0 + 64 + sr) * DM + k0 + sc];
        *(uint4*)&Bs[sr * 32 + sc]        = *(const uint4*)&W[(size_t)(n0 + sr) * DM + k0 + sc];
        *(uint4*)&Bs[(sr + 64) * 32 + sc] = *(const uint4*)&W[(size_t)(n0 + 64 + sr) * DM + k0 + sc];
        __syncthreads();
        bf16x8 af[4], bv[4];
        #pragma unroll
        for (int mi = 0; mi < 4; ++mi)
            af[mi] = *(const bf16x8*)&As[(wm + mi * 16 + fr) * 32 + fk];
        #pragma unroll
        for (int ni = 0; ni < 4; ++ni)
            bv[ni] = *(const bf16x8*)&Bs[(wn + ni * 16 + fr) * 32 + fk];
        #pragma unroll
        for (int mi = 0; mi < 4; ++mi)
            #pragma unroll
            for (int ni = 0; ni < 4; ++ni)
                acc[mi][ni] = __builtin_amdgcn_mfma_f32_16x16x32_bf16(af[mi], bv[ni], acc[mi][ni], 0, 0, 0);
        __syncthreads();
    }
    // C/D layout: col = lane&15, row = (lane>>4)*4 + reg  [verified m89/m91]
    const int cr = (lane >> 4) * 4, cc = lane & 15;
    #pragma unroll
    for (int mi = 0; mi < 4; ++mi) {
        #pragma unroll
        for (int ni = 0; ni < 4; ++ni) {
            const int n = n0 + wn + ni * 16 + cc;
            const float bn = bias[n];
            #pragma unroll
            for (int v = 0; v < 4; ++v) {
                const int m = m0 + wm + mi * 16 + cr + v;
                const float val = acc[mi][ni][v] + bn;
                if (MODE == 0) {
                    const int b_ = m >> 11, t = m & (SEQ - 1);
                    const int h = n >> 6, hd = n & 63;
                    ((bf16_t*)outp)[(((size_t)(b_ * NH + h)) * SEQ + t) * HD + hd] = (__bf16)val;
                } else {
                    ((float*)outp)[(size_t)m * DM + n] = val;
                }
            }
        }
    }
}

// ---------------- V transpose: [B,H,T,HD] -> [B,H,HD,T] (both bf16) ----------------
__global__ __launch_bounds__(256)
void transpose_v(const bf16_t* __restrict__ Vb, bf16_t* __restrict__ Vt)
{
    const int bh = blockIdx.y, t0 = blockIdx.x * 64;
    __shared__ bf16_t L[64][72];
    const bf16_t* src = Vb + (size_t)bh * SEQ * HD;
    bf16_t* dst = Vt + (size_t)bh * HD * SEQ;
    for (int i = threadIdx.x; i < 64 * 64; i += 256) {
        int r = i >> 6, c = i & 63;
        L[c][r] = src[(size_t)(t0 + r) * HD + c];
    }
    __syncthreads();
    for (int i = threadIdx.x; i < 64 * 64; i += 256) {
        int hd = i >> 6, c = i & 63;
        dst[(size_t)hd * SEQ + t0 + c] = L[hd][c];
    }
}

// ---------------- scores: attn = scale * Q @ K^T, mask -> -inf (fp32 out) ----------------
__global__ __launch_bounds__(256)
void scores_mfma(const bf16_t* __restrict__ Q, const bf16_t* __restrict__ K,
                 const int* __restrict__ mask, float* __restrict__ attn)
{
    __shared__ __align__(16) bf16_t As[128 * 32];
    __shared__ __align__(16) bf16_t Bs[128 * 32];
    const int bh = blockIdx.z, b = bh >> 4;
    const int n0 = blockIdx.x * 128, m0 = blockIdx.y * 128;
    const bf16_t* Qb = Q + (size_t)bh * SEQ * HD;
    const bf16_t* Kb = K + (size_t)bh * SEQ * HD;
    const int tid = threadIdx.x, lane = tid & 63, wave = tid >> 6;
    const int wm = (wave >> 1) * 64, wn = (wave & 1) * 64;
    const int sr = tid >> 2, sc = (tid & 3) * 8;
    const int fr = lane & 15, fk = (lane >> 4) * 8;
    f32x4 acc[4][4] = {};
    #pragma unroll
    for (int k0 = 0; k0 < HD; k0 += 32) {
        *(uint4*)&As[sr * 32 + sc]        = *(const uint4*)&Qb[(size_t)(m0 + sr) * HD + k0 + sc];
        *(uint4*)&As[(sr + 64) * 32 + sc] = *(const uint4*)&Qb[(size_t)(m0 + 64 + sr) * HD + k0 + sc];
        *(uint4*)&Bs[sr * 32 + sc]        = *(const uint4*)&Kb[(size_t)(n0 + sr) * HD + k0 + sc];
        *(uint4*)&Bs[(sr + 64) * 32 + sc] = *(const uint4*)&Kb[(size_t)(n0 + 64 + sr) * HD + k0 + sc];
        __syncthreads();
        bf16x8 af[4], bv[4];
        #pragma unroll
        for (int mi = 0; mi < 4; ++mi)
            af[mi] = *(const bf16x8*)&As[(wm + mi * 16 + fr) * 32 + fk];
        #pragma unroll
        for (int ni = 0; ni < 4; ++ni)
            bv[ni] = *(const bf16x8*)&Bs[(wn + ni * 16 + fr) * 32 + fk];
        #pragma unroll
        for (int mi = 0; mi < 4; ++mi)
            #pragma unroll
            for (int ni = 0; ni < 4; ++ni)
                acc[mi][ni] = __builtin_amdgcn_mfma_f32_16x16x32_bf16(af[mi], bv[ni], acc[mi][ni], 0, 0, 0);
        __syncthreads();
    }
    float* Ab = attn + (size_t)bh * SEQ * SEQ;
    const int cr = (lane >> 4) * 4, cc = lane & 15;
    #pragma unroll
    for (int ni = 0; ni < 4; ++ni) {
        const int n = n0 + wn + ni * 16 + cc;
        const bool dead = (mask[b * SEQ + n] == 0);
        #pragma unroll
        for (int mi = 0; mi < 4; ++mi) {
            #pragma unroll
            for (int v = 0; v < 4; ++v) {
                const int m = m0 + wm + mi * 16 + cr + v;
                float s = acc[mi][ni][v] * 0.125f;   // 1/sqrt(64)
                if (dead) s = -INFINITY;
                Ab[(size_t)m * SEQ + n] = s;
            }
        }
    }
}

// ---------------- in-place fp32 row softmax over 2048 ----------------
__global__ __launch_bounds__(256)
void softmax_kernel(float* __restrict__ attn)
{
    float4* p4 = (float4*)(attn + (size_t)blockIdx.x * SEQ);
    const int tid = threadIdx.x;
    float4 v0 = p4[tid], v1 = p4[tid + 256];
    float m = fmaxf(fmaxf(fmaxf(v0.x, v0.y), fmaxf(v0.z, v0.w)),
                    fmaxf(fmaxf(v1.x, v1.y), fmaxf(v1.z, v1.w)));
    #pragma unroll
    for (int off = 32; off > 0; off >>= 1) m = fmaxf(m, __shfl_down(m, off));
    __shared__ float red[4];
    __shared__ float bc;
    if ((tid & 63) == 0) red[tid >> 6] = m;
    __syncthreads();
    if (tid == 0) bc = fmaxf(fmaxf(red[0], red[1]), fmaxf(red[2], red[3]));
    __syncthreads();
    m = bc;
    v0.x = __expf(v0.x - m); v0.y = __expf(v0.y - m);
    v0.z = __expf(v0.z - m); v0.w = __expf(v0.w - m);
    v1.x = __expf(v1.x - m); v1.y = __expf(v1.y - m);
    v1.z = __expf(v1.z - m); v1.w = __expf(v1.w - m);
    float s = v0.x + v0.y + v0.z + v0.w + v1.x + v1.y + v1.z + v1.w;
    #pragma unroll
    for (int off = 32; off > 0; off >>= 1) s += __shfl_down(s, off);
    __syncthreads();
    if ((tid & 63) == 0) red[tid >> 6] = s;
    __syncthreads();
    if (tid == 0) bc = red[0] + red[1] + red[2] + red[3];
    __syncthreads();
    const float inv = 1.f / bc;
    v0.x *= inv; v0.y *= inv; v0.z *= inv; v0.w *= inv;
    v1.x *= inv; v1.y *= inv; v1.z *= inv; v1.w *= inv;
    p4[tid] = v0; p4[tid + 256] = v1;
}

// ---------------- context: ctxb[b,t,h*64+hd] = attn @ V  (bf16 out) ----------------
// attn fp32 [bh,T,T] (converted to bf16 during staging); Vt bf16 [bh,HD,T].
// Tile: 256 q-rows x 64 cols, BK=32; 4 waves, each 64 rows x 64 cols.
__global__ __launch_bounds__(256)
void context_mfma(const float* __restrict__ attn, const bf16_t* __restrict__ Vt,
                  bf16_t* __restrict__ ctxb)
{
    __shared__ __align__(16) bf16_t As[256 * 32];  // 16 KB
    __shared__ __align__(16) bf16_t Bs[64 * 32];   // 4 KB
    const int bh = blockIdx.y, q0 = blockIdx.x * 256;
    const int b = bh >> 4, h = bh & 15;
    const float* Ab = attn + (size_t)bh * SEQ * SEQ;
    const bf16_t* Vtb = Vt + (size_t)bh * HD * SEQ;
    const int tid = threadIdx.x, lane = tid & 63, wave = tid >> 6;
    const int wm = wave * 64;
    const int ar = tid >> 3, ac = (tid & 7) * 4;   // A staging: 32 rows/pass, 8 k-chunks of 4
    const int br = tid >> 2, bc2 = (tid & 3) * 8;  // B staging: 64 rows, 4 k-chunks of 8
    const int fr = lane & 15, fk = (lane >> 4) * 8;
    f32x4 acc[4][4] = {};
    for (int k0 = 0; k0 < SEQ; k0 += 32) {
        #pragma unroll
        for (int rr = 0; rr < 8; ++rr) {
            const int row = rr * 32 + ar;
            float4 f = *(const float4*)&Ab[(size_t)(q0 + row) * SEQ + k0 + ac];
            bf16x4 hv;
            hv.x = (__bf16)f.x; hv.y = (__bf16)f.y; hv.z = (__bf16)f.z; hv.w = (__bf16)f.w;
            *(bf16x4*)&As[row * 32 + ac] = hv;
        }
        *(uint4*)&Bs[br * 32 + bc2] = *(const uint4*)&Vtb[(size_t)br * SEQ + k0 + bc2];
        __syncthreads();
        bf16x8 af[4], bv[4];
        #pragma unroll
        for (int mi = 0; mi < 4; ++mi)
            af[mi] = *(const bf16x8*)&As[(wm + mi * 16 + fr) * 32 + fk];
        #pragma unroll
        for (int ni = 0; ni < 4; ++ni)
            bv[ni] = *(const bf16x8*)&Bs[(ni * 16 + fr) * 32 + fk];
        #pragma unroll
        for (int mi = 0; mi < 4; ++mi)
            #pragma unroll
            for (int ni = 0; ni < 4; ++ni)
                acc[mi][ni] = __builtin_amdgcn_mfma_f32_16x16x32_bf16(af[mi], bv[ni], acc[mi][ni], 0, 0, 0);
        __syncthreads();
    }
    const int cr = (lane >> 4) * 4, cc = lane & 15;
    #pragma unroll
    for (int mi = 0; mi < 4; ++mi) {
        #pragma unroll
        for (int ni = 0; ni < 4; ++ni) {
            #pragma unroll
            for (int v = 0; v < 4; ++v) {
                const int t = q0 + wm + mi * 16 + cr + v;
                const int n = ni * 16 + cc;   // hd
                ctxb[((size_t)b * SEQ + t) * DM + h * HD + n] = (__bf16)acc[mi][ni][v];
            }
        }
    }
}

extern "C" void kernel_launch(void* const* d_in, const int* in_sizes, int n_in,
                              void* d_out, int out_size, void* d_ws, size_t ws_size,
                              hipStream_t stream)
{
    const float* x   = (const float*)d_in[0];
    const int*  mask = (const int*)d_in[1];
    const float* Wq  = (const float*)d_in[2];
    const float* bq  = (const float*)d_in[3];
    const float* Wk  = (const float*)d_in[4];
    const float* bk  = (const float*)d_in[5];
    const float* Wv  = (const float*)d_in[6];
    const float* bv  = (const float*)d_in[7];
    const float* Wo  = (const float*)d_in[8];
    const float* bo  = (const float*)d_in[9];

    float* out  = (float*)d_out;                       // [B,T,D]
    float* attn = out + (size_t)BATCH * SEQ * DM;      // [B,H,T,T] fp32

    const size_t NX = (size_t)MTOT * DM;               // 4,194,304
    const size_t NW = (size_t)DM * DM;                 // 1,048,576
    const size_t NQ = (size_t)BATCH * NH * SEQ * HD;   // 4,194,304

    bf16_t* xb   = (bf16_t*)d_ws;
    bf16_t* Wqb  = xb + NX;
    bf16_t* Wkb  = Wqb + NW;
    bf16_t* Wvb  = Wkb + NW;
    bf16_t* Wob  = Wvb + NW;
    bf16_t* Qb   = Wob + NW;
    bf16_t* Kb   = Qb + NQ;
    bf16_t* Vb   = Kb + NQ;
    bf16_t* Vt   = Vb + NQ;
    bf16_t* ctxb = Vt + NQ;

    cvt_bf16<<<dim3(NX / 1024), 256, 0, stream>>>(x, xb, (int)NX);
    cvt_bf16<<<dim3(NW / 1024), 256, 0, stream>>>(Wq, Wqb, (int)NW);
    cvt_bf16<<<dim3(NW / 1024), 256, 0, stream>>>(Wk, Wkb, (int)NW);
    cvt_bf16<<<dim3(NW / 1024), 256, 0, stream>>>(Wv, Wvb, (int)NW);
    cvt_bf16<<<dim3(NW / 1024), 256, 0, stream>>>(Wo, Wob, (int)NW);

    dim3 g1(DM / 128, MTOT / 128);                     // (8, 32)
    gemm_bt<0><<<g1, 256, 0, stream>>>(xb, Wqb, bq, Qb);
    gemm_bt<0><<<g1, 256, 0, stream>>>(xb, Wkb, bk, Kb);
    gemm_bt<0><<<g1, 256, 0, stream>>>(xb, Wvb, bv, Vb);

    transpose_v<<<dim3(SEQ / 64, BATCH * NH), 256, 0, stream>>>(Vb, Vt);

    scores_mfma<<<dim3(SEQ / 128, SEQ / 128, BATCH * NH), 256, 0, stream>>>(Qb, Kb, mask, attn);

    softmax_kernel<<<dim3(BATCH * NH * SEQ), 256, 0, stream>>>(attn);

    context_mfma<<<dim3(SEQ / 256, BATCH * NH), 256, 0, stream>>>(attn, Vt, ctxb);

    gemm_bt<1><<<g1, 256, 0, stream>>>(ctxb, Wob, bo, out);
}